// Round 2
// 271.698 us; speedup vs baseline: 1.0841x; 1.0841x over previous
//
#include <hip/hip_runtime.h>
#include <math.h>

#define B 256
#define C 1000
#define D 128
#define QN 262144

// output layout (floats):
// [0]        output        B*C      = 256000
// [256000]   output2       B*C      = 256000
// [512000]   features      (2B+Q)*D = 33619968
// [34131968] pseudo_labels (2B+Q)   = 262656
// [34394624] score_prot    B*C      = 256000
// [34650624] protos        C*D      = 128000
#define OFF_FEAT   512000
#define OFF_LBL    34131968
#define OFF_SCORE  34394624
#define OFF_PROTO  34650624

#define N_Q4   (QN * D / 4)          /* 8388608 float4: queue -> features[2B:] */
#define N_O4   (B * C / 4)           /* 64000 */
#define N_F4   (B * D / 4)           /* 8192  */
#define N_P4   (QN / 4)              /* 65536 */

#define DST_Q4   ((OFF_FEAT + 2 * B * D) / 4)
#define DST_O24  (B * C / 4)
#define DST_QF4  (OFF_FEAT / 4)
#define DST_KF4  (OFF_FEAT / 4 + N_F4)
#define DST_P4   ((OFF_LBL + 2 * B) / 4)

// small-segment ranges (float4 indices)
#define SM_O2  (N_O4)                         /* after: output2 */
#define SM_Q   (2 * N_O4)                     /* after: q       */
#define SM_K   (2 * N_O4 + N_F4)              /* after: k       */
#define SM_P   (2 * N_O4 + 2 * N_F4)          /* after: pseudo  */
#define SM_TOT (2 * N_O4 + 2 * N_F4 + N_P4)   /* 209920 float4  */

// queue copy tiling: 1024 float4 (16 KB) per tile/block
#define Q_TILES   (N_Q4 / 1024)               /* 8192 */
#define K1_TILES  640                         /* ~3 µs of BW work to hide argmax */
#define K2_TILES  (Q_TILES - K1_TILES)        /* 7552 */

// K2 role boundaries (compute first so it dispatches earliest)
#define R_EMA    500                          /* 2 classes per block */
#define R_SCORE  (R_EMA + B)                  /* 756  */
#define SM_BLKS  ((SM_TOT + 255) / 256)       /* 820  */
#define R_SMALL  (R_SCORE + SM_BLKS)          /* 1576 */
#define K2_GRID  (R_SMALL + K2_TILES)         /* 9128 */

// ---------------- K1: argmax (blocks 0..B-1) + leading queue-copy slice --------
__global__ __launch_bounds__(256) void k1_kernel(
    const float* __restrict__ output,
    const float* __restrict__ partial_Y,
    const float4* __restrict__ queue,
    int* __restrict__ labels,
    float* __restrict__ out)
{
    const int tid = threadIdx.x;

    if (blockIdx.x >= B) {
        // queue copy tile: keep HBM busy while argmax blocks run
        const size_t base = (size_t)(blockIdx.x - B) * 1024 + tid;
        float4* __restrict__ dst = (float4*)out + DST_Q4;
        float4 a = queue[base];
        float4 b = queue[base + 256];
        float4 c = queue[base + 512];
        float4 d = queue[base + 768];
        dst[base]       = a;
        dst[base + 256] = b;
        dst[base + 512] = c;
        dst[base + 768] = d;
        return;
    }

    // argmax of output*partial_Y per row (first-occurrence ties)
    const int b = blockIdx.x;
    const float* row = output + (size_t)b * C;
    const float* msk = partial_Y + (size_t)b * C;

    float best = -INFINITY;
    int bidx = C;
    for (int c = tid; c < C; c += 256) {
        float v = row[c] * msk[c];
        if (v > best) { best = v; bidx = c; }  // strict > keeps first occurrence
    }

    __shared__ float sv[256];
    __shared__ int   si[256];
    sv[tid] = best; si[tid] = bidx;
    __syncthreads();
    for (int s = 128; s > 0; s >>= 1) {
        if (tid < s) {
            float v2 = sv[tid + s]; int i2 = si[tid + s];
            if (v2 > sv[tid] || (v2 == sv[tid] && i2 < si[tid])) {
                sv[tid] = v2; si[tid] = i2;
            }
        }
        __syncthreads();
    }
    if (tid == 0) {
        int lab = si[0];
        labels[b] = lab;
        float f = (float)lab;
        out[OFF_LBL + b]     = f;
        out[OFF_LBL + B + b] = f;
    }
}

// ---------------- K2: ema + scoreprot + copysmall + remaining queue copy -------
__global__ __launch_bounds__(256) void k2_kernel(
    const float* __restrict__ q,
    const float* __restrict__ kk,
    const float* __restrict__ output,
    const float* __restrict__ output2,
    const float* __restrict__ prototypes,
    const float4* __restrict__ queue,
    const float* __restrict__ queue_pseudo,
    const int* __restrict__ labels,
    float* __restrict__ out)
{
    const int bid = blockIdx.x;
    const int tid = threadIdx.x;

    if (bid < R_EMA) {
        // EMA scatter (sequential-in-b per class) + L2 normalize; 2 classes/block
        __shared__ int   lab[B];
        __shared__ float ss[256];
        const int c = 2 * bid + (tid >> 7);   // class for this half-block
        const int d = tid & 127;              // dim
        for (int i = tid; i < B; i += 256) lab[i] = labels[i];
        __syncthreads();

        float val = prototypes[(size_t)c * D + d];
        for (int b = 0; b < B; ++b) {
            if (lab[b] == c) {                // half-block-uniform branch (2 waves)
                val = val * 0.99f + 0.01f * q[(size_t)b * D + d];
            }
        }

        ss[tid] = val * val;
        __syncthreads();
        for (int s = 64; s > 0; s >>= 1) {
            if (d < s) ss[tid] += ss[tid + s];
            __syncthreads();
        }
        float r = fmaxf(sqrtf(ss[tid & 128]), 1e-12f);  // ss[0] or ss[128]
        out[OFF_PROTO + (size_t)c * D + d] = val / r;
        return;
    }

    if (bid < R_SCORE) {
        // score_prot = softmax(q @ P^T) per row (uses ORIGINAL prototypes)
        const int b = bid - R_EMA;
        __shared__ float qs[D];
        __shared__ float logits[C];
        __shared__ float red[256];
        if (tid < D) qs[tid] = q[(size_t)b * D + tid];
        __syncthreads();

        for (int c = tid; c < C; c += 256) {
            const float4* p4 = (const float4*)(prototypes + (size_t)c * D);
            const float4* q4 = (const float4*)qs;
            float acc = 0.f;
            #pragma unroll
            for (int d = 0; d < D / 4; ++d) {
                float4 pv = p4[d];
                float4 qv = q4[d];
                acc += pv.x * qv.x + pv.y * qv.y + pv.z * qv.z + pv.w * qv.w;
            }
            logits[c] = acc;
        }
        __syncthreads();

        float lm = -INFINITY;
        for (int c = tid; c < C; c += 256) lm = fmaxf(lm, logits[c]);
        red[tid] = lm;
        __syncthreads();
        for (int s = 128; s > 0; s >>= 1) {
            if (tid < s) red[tid] = fmaxf(red[tid], red[tid + s]);
            __syncthreads();
        }
        const float m = red[0];
        __syncthreads();

        float psum = 0.f;
        for (int c = tid; c < C; c += 256) {
            float e = expf(logits[c] - m);
            logits[c] = e;
            psum += e;
        }
        red[tid] = psum;
        __syncthreads();
        for (int s = 128; s > 0; s >>= 1) {
            if (tid < s) red[tid] += red[tid + s];
            __syncthreads();
        }
        const float denom = red[0];

        for (int c = tid; c < C; c += 256)
            out[OFF_SCORE + (size_t)b * C + c] = logits[c] / denom;
        return;
    }

    if (bid < R_SMALL) {
        // small segments: output, output2, q->feat, k->feat, queue_pseudo->labels
        const size_t i = (size_t)(bid - R_SCORE) * 256 + tid;
        float4* __restrict__ out4 = (float4*)out;
        if (i < SM_O2)       out4[i]                     = ((const float4*)output)[i];
        else if (i < SM_Q)   out4[DST_O24 + (i - SM_O2)] = ((const float4*)output2)[i - SM_O2];
        else if (i < SM_K)   out4[DST_QF4 + (i - SM_Q)]  = ((const float4*)q)[i - SM_Q];
        else if (i < SM_P)   out4[DST_KF4 + (i - SM_K)]  = ((const float4*)kk)[i - SM_K];
        else if (i < SM_TOT) out4[DST_P4 + (i - SM_P)]   = ((const float4*)queue_pseudo)[i - SM_P];
        return;
    }

    // remaining queue copy tiles
    const size_t base = ((size_t)(bid - R_SMALL) + K1_TILES) * 1024 + tid;
    float4* __restrict__ dst = (float4*)out + DST_Q4;
    float4 a = queue[base];
    float4 b = queue[base + 256];
    float4 c = queue[base + 512];
    float4 d = queue[base + 768];
    dst[base]       = a;
    dst[base + 256] = b;
    dst[base + 512] = c;
    dst[base + 768] = d;
}

extern "C" void kernel_launch(void* const* d_in, const int* in_sizes, int n_in,
                              void* d_out, int out_size, void* d_ws, size_t ws_size,
                              hipStream_t stream) {
    const float* q            = (const float*)d_in[0];
    const float* k            = (const float*)d_in[1];
    const float* output       = (const float*)d_in[2];
    const float* output2      = (const float*)d_in[3];
    const float* partial_Y    = (const float*)d_in[4];
    const float* prototypes   = (const float*)d_in[5];
    const float* queue        = (const float*)d_in[6];
    const float* queue_pseudo = (const float*)d_in[7];

    float* out  = (float*)d_out;
    int* labels = (int*)d_ws;

    // K1: argmax (needed by ema) + small queue-copy slice to keep HBM busy
    k1_kernel<<<B + K1_TILES, 256, 0, stream>>>(
        output, partial_Y, (const float4*)queue, labels, out);

    // K2: everything else, compute roles at low block indices so they
    // dispatch first and hide under the BW-bound queue copy
    k2_kernel<<<K2_GRID, 256, 0, stream>>>(
        q, k, output, output2, prototypes,
        (const float4*)queue, queue_pseudo, labels, out);
}